// Round 1
// baseline (604.441 us; speedup 1.0000x reference)
//
#include <hip/hip_runtime.h>
#include <hip/hip_bf16.h>
#include <math.h>

// EmbeddingAlignerOT on MI355X.
// Pipeline: cvt(s,W)->bf16 | prep_g(norm+cvt) | GEMM1 t=s@W^T+b (bf16 MFMA)
//   | norm_t | weights | GEMM2 K=exp(-cost*10) | transpose K | sinkhorn
//   (12 real iters + exact scalar extrapolation to 100) | gTv=v*g^T | GEMM3
//   aligned = u.*(K @ gTv)  -> d_out fp32.
// Workspace layout (needs ~103.2 MB):
//   [0, 32M)      s_bf16  -> reused as K (16M) + KT (16M) after gemm1
//   [32M, 34M)    W_bf16
//   [34M, 66M)    g_bf16
//   [66M, 98M)    t_bf16  -> reused as gTv after gemm2
//   [98M, ...)    s2,g2,sw,gw,u,v (6 x 64KB fp32)

typedef __bf16 bf16_t;
typedef __bf16 bf16x8 __attribute__((ext_vector_type(8)));
typedef float  f32x4  __attribute__((ext_vector_type(4)));

#define NBATCH 32
#define NS 512
#define NG 512
#define NH 1024
#define M_REAL 12
#define N_TOT 100

__device__ __forceinline__ void async_copy16(const void* gsrc, void* ldst) {
  __builtin_amdgcn_global_load_lds(
      (__attribute__((address_space(1))) void*)gsrc,
      (__attribute__((address_space(3))) void*)ldst, 16, 0, 0);
}

// ---------- fp32 -> bf16 convert, 8 elems/thread ----------
__global__ __launch_bounds__(256) void cvt_bf16_kernel(const float* __restrict__ in,
                                                       bf16_t* __restrict__ out, int n8) {
  int i = blockIdx.x * 256 + threadIdx.x;
  if (i >= n8) return;
  const float4* p = (const float4*)in + (size_t)i * 2;
  float4 a = p[0], b = p[1];
  bf16x8 o;
  o[0] = (__bf16)a.x; o[1] = (__bf16)a.y; o[2] = (__bf16)a.z; o[3] = (__bf16)a.w;
  o[4] = (__bf16)b.x; o[5] = (__bf16)b.y; o[6] = (__bf16)b.z; o[7] = (__bf16)b.w;
  ((bf16x8*)out)[i] = o;
}

// ---------- target: convert to bf16 + fp32 row norms ----------
__global__ __launch_bounds__(128) void prep_g_kernel(const float* __restrict__ g,
                                                     bf16_t* __restrict__ gb,
                                                     float* __restrict__ g2) {
  int row = blockIdx.x;   // B*G rows of length NH
  int t = threadIdx.x;    // 128
  const float* rp = g + (size_t)row * NH + t * 8;
  float4 a = *(const float4*)rp;
  float4 b = *(const float4*)(rp + 4);
  bf16x8 o;
  o[0] = (__bf16)a.x; o[1] = (__bf16)a.y; o[2] = (__bf16)a.z; o[3] = (__bf16)a.w;
  o[4] = (__bf16)b.x; o[5] = (__bf16)b.y; o[6] = (__bf16)b.z; o[7] = (__bf16)b.w;
  ((bf16x8*)(gb + (size_t)row * NH))[t] = o;
  float ss = a.x*a.x + a.y*a.y + a.z*a.z + a.w*a.w
           + b.x*b.x + b.y*b.y + b.z*b.z + b.w*b.w;
  #pragma unroll
  for (int ofs = 32; ofs > 0; ofs >>= 1) ss += __shfl_down(ss, ofs);
  __shared__ float wsum[2];
  if ((t & 63) == 0) wsum[t >> 6] = ss;
  __syncthreads();
  if (t == 0) g2[row] = wsum[0] + wsum[1];
}

// ---------- row norms of bf16 t ----------
__global__ __launch_bounds__(128) void norm_t_kernel(const bf16_t* __restrict__ tb,
                                                     float* __restrict__ s2) {
  int row = blockIdx.x;
  int t = threadIdx.x;
  bf16x8 v = ((const bf16x8*)(tb + (size_t)row * NH))[t];
  float ss = 0.f;
  #pragma unroll
  for (int e = 0; e < 8; e++) { float f = (float)v[e]; ss += f * f; }
  #pragma unroll
  for (int ofs = 32; ofs > 0; ofs >>= 1) ss += __shfl_down(ss, ofs);
  __shared__ float wsum[2];
  if ((t & 63) == 0) wsum[t >> 6] = ss;
  __syncthreads();
  if (t == 0) s2[row] = wsum[0] + wsum[1];
}

// ---------- adjusted weights: w = mask*(sqrt(n2)+EPS)+EPS, normalized ----------
__global__ __launch_bounds__(512) void weights_kernel(const float* __restrict__ n2,
                                                      const int* __restrict__ mask,
                                                      float* __restrict__ wout) {
  int bb = blockIdx.x, t = threadIdx.x;
  int idx = bb * 512 + t;
  float mag = sqrtf(n2[idx]) + 1e-12f;
  float w = (float)mask[idx] * mag + 1e-12f;
  float ss = w;
  #pragma unroll
  for (int ofs = 32; ofs > 0; ofs >>= 1) ss += __shfl_down(ss, ofs);
  __shared__ float red[8];
  __shared__ float tot;
  if ((t & 63) == 0) red[t >> 6] = ss;
  __syncthreads();
  if (t == 0) {
    float x = 0.f;
    #pragma unroll
    for (int i = 0; i < 8; i++) x += red[i];
    tot = fmaxf(x, 1e-12f);
  }
  __syncthreads();
  wout[idx] = w / tot;
}

// ---------- C = A * B^T, 128x128 tile, BK=32, 4 waves, bf16 MFMA ----------
// MODE 0: t = A@B^T + bias, bf16 store           (gemm1)
// MODE 1: K = exp(-10*(sqrt(s2+g2-2C)*sw*gw+eps)) bf16 store (gemm2, batched)
// MODE 2: out = u .* C, fp32 store               (gemm3, batched)
template <int MODE>
__global__ __launch_bounds__(256) void gemm_bt_kernel(
    const bf16_t* __restrict__ A, const bf16_t* __restrict__ Bm, int K_len,
    size_t strideAb, size_t strideBb,
    void* __restrict__ outp, size_t strideOb, int ldc,
    const float* __restrict__ bias,
    const float* __restrict__ s2, const float* __restrict__ g2,
    const float* __restrict__ sw, const float* __restrict__ gw,
    const float* __restrict__ uvec) {
  __shared__ bf16_t lA[128 * 32];
  __shared__ bf16_t lB[128 * 32];
  const int tid = threadIdx.x, lane = tid & 63, wave = tid >> 6;
  const int wr = wave >> 1, wc = wave & 1;
  const int bz = blockIdx.z;
  const bf16_t* Ab = A + (size_t)bz * strideAb;
  const bf16_t* Bb = Bm + (size_t)bz * strideBb;
  const int m0 = blockIdx.y * 128, n0 = blockIdx.x * 128;
  const int rA = lane >> 2;       // row within 16-row staging group
  const int c8 = (lane & 3) * 8;  // bf16 col offset of this lane's 16B chunk

  f32x4 acc[4][4];
  #pragma unroll
  for (int i = 0; i < 4; i++)
    #pragma unroll
    for (int j = 0; j < 4; j++) { f32x4 z = {0.f, 0.f, 0.f, 0.f}; acc[i][j] = z; }

  for (int kt = 0; kt < K_len; kt += 32) {
    if (kt) __syncthreads();
    #pragma unroll
    for (int c = 0; c < 2; c++) {
      int rg = (c * 4 + wave) * 16;
      async_copy16(Ab + (size_t)(m0 + rg + rA) * K_len + kt + c8, &lA[rg * 32]);
      async_copy16(Bb + (size_t)(n0 + rg + rA) * K_len + kt + c8, &lB[rg * 32]);
    }
    __syncthreads();  // vmcnt(0) drained by compiler before barrier
    bf16x8 af[4], bf[4];
    #pragma unroll
    for (int m = 0; m < 4; m++)
      af[m] = *(const bf16x8*)&lA[(wr * 64 + m * 16 + (lane & 15)) * 32 + (lane >> 4) * 8];
    #pragma unroll
    for (int n = 0; n < 4; n++)
      bf[n] = *(const bf16x8*)&lB[(wc * 64 + n * 16 + (lane & 15)) * 32 + (lane >> 4) * 8];
    #pragma unroll
    for (int m = 0; m < 4; m++)
      #pragma unroll
      for (int n = 0; n < 4; n++)
        acc[m][n] = __builtin_amdgcn_mfma_f32_16x16x32_bf16(af[m], bf[n], acc[m][n], 0, 0, 0);
  }

  // epilogue: C/D frag mapping col=lane&15, row=(lane>>4)*4+j
  const int bo = bz * 512;
  const int row_base = m0 + wr * 64, col_base = n0 + wc * 64;
  const int r_off = (lane >> 4) * 4, c_off = lane & 15;
  #pragma unroll
  for (int m = 0; m < 4; m++) {
    #pragma unroll
    for (int n = 0; n < 4; n++) {
      #pragma unroll
      for (int j = 0; j < 4; j++) {
        int gm = row_base + m * 16 + r_off + j;
        int gn = col_base + n * 16 + c_off;
        float val = acc[m][n][j];
        if (MODE == 0) {
          ((bf16_t*)outp)[(size_t)gm * ldc + gn] = (__bf16)(val + bias[gn]);
        } else if (MODE == 1) {
          float sq = s2[bo + gm] + g2[bo + gn] - 2.0f * val;
          float d = sqrtf(fmaxf(sq, 0.0f));
          float cost = d * sw[bo + gm] * gw[bo + gn] + 1e-12f;
          ((bf16_t*)outp + (size_t)bz * strideOb)[(size_t)gm * ldc + gn] =
              (__bf16)expf(-10.0f * cost);
        } else {
          ((float*)outp + (size_t)bz * strideOb)[(size_t)gm * ldc + gn] =
              uvec[bo + gm] * val;
        }
      }
    }
  }
}

// ---------- K [S][G] -> KT [G][S] per batch ----------
__global__ __launch_bounds__(256) void transpose_k_kernel(const bf16_t* __restrict__ in,
                                                          bf16_t* __restrict__ out) {
  __shared__ bf16_t tl[32][33];
  size_t bo = (size_t)blockIdx.z * (NS * NG);
  int r0 = blockIdx.y * 32, c0 = blockIdx.x * 32;
  int tx = threadIdx.x & 31, ty = threadIdx.x >> 5;  // 8 rows/pass
  #pragma unroll
  for (int p = 0; p < 4; p++)
    tl[ty + p * 8][tx] = in[bo + (size_t)(r0 + ty + p * 8) * NG + c0 + tx];
  __syncthreads();
  #pragma unroll
  for (int p = 0; p < 4; p++)
    out[bo + (size_t)(c0 + ty + p * 8) * NS + r0 + tx] = tl[tx][ty + p * 8];
}

// ---------- gTv[h][g] = v[g] * g_bf[g][h] per batch ----------
__global__ __launch_bounds__(256) void make_gtv_kernel(const bf16_t* __restrict__ g,
                                                       const float* __restrict__ v,
                                                       bf16_t* __restrict__ out) {
  __shared__ bf16_t tl[32][33];
  size_t bi = (size_t)blockIdx.z * (NG * NH);
  int r0 = blockIdx.y * 32, c0 = blockIdx.x * 32;  // r over G, c over H
  int tx = threadIdx.x & 31, ty = threadIdx.x >> 5;
  #pragma unroll
  for (int p = 0; p < 4; p++)
    tl[ty + p * 8][tx] = g[bi + (size_t)(r0 + ty + p * 8) * NH + c0 + tx];
  __syncthreads();
  int vb = blockIdx.z * NG;
  #pragma unroll
  for (int p = 0; p < 4; p++) {
    int h = c0 + ty + p * 8, gg = r0 + tx;
    out[bi + (size_t)h * NG + gg] = (__bf16)((float)tl[tx][ty + p * 8] * v[vb + gg]);
  }
}

// ---------- Sinkhorn: 12 real iterations + exact scalar extrapolation ----------
// After shape convergence (Hilbert contraction of K ~1e-4/iter), each iteration
// scales u,v by elementwise-constant factors with log-ratio rho_{k+1}=fi^2*rho_k
// exactly. u100 = u12*exp(rho_u * sum_{j=1..88} fi^(2j)).
__global__ __launch_bounds__(1024) void sinkhorn_kernel(
    const bf16_t* __restrict__ Kmat, const bf16_t* __restrict__ KT,
    const float* __restrict__ swv, const float* __restrict__ gwv,
    float* __restrict__ u_out, float* __restrict__ v_out) {
  __shared__ float u[512], v[512], av[512], bv[512];
  __shared__ float part[1024];
  __shared__ float scal[2];
  const int b = blockIdx.x, t = threadIdx.x;
  const bf16_t* Kb = Kmat + (size_t)b * NS * NG;
  const bf16_t* KTb = KT + (size_t)b * NS * NG;
  if (t < 512) {
    av[t] = swv[b * 512 + t];
    bv[t] = gwv[b * 512 + t];
    v[t] = 1.0f / 512.0f;
  }
  __syncthreads();
  const float fi = 10.0f / 10.1f;
  const int s = t >> 1, half = t & 1;
  const bf16_t* rowK = Kb + (size_t)s * NG + half * 256;
  const bf16_t* rowKT = KTb + (size_t)s * NS + half * 256;
  float rho_u = 0.f, rho_v = 0.f;

  for (int it = 1; it <= M_REAL; ++it) {
    // ---- u phase: Kv ----
    {
      float sum = 0.f;
      #pragma unroll 4
      for (int j8 = 0; j8 < 32; j8++) {
        bf16x8 kv = *(const bf16x8*)(rowK + j8 * 8);
        const float4* vp = (const float4*)&v[half * 256 + j8 * 8];
        float4 v0 = vp[0], v1 = vp[1];
        sum += (float)kv[0] * v0.x + (float)kv[1] * v0.y + (float)kv[2] * v0.z +
               (float)kv[3] * v0.w + (float)kv[4] * v1.x + (float)kv[5] * v1.y +
               (float)kv[6] * v1.z + (float)kv[7] * v1.w;
      }
      part[t] = sum;
    }
    __syncthreads();
    if (t < 512) {
      float Kv = part[2 * t] + part[2 * t + 1];
      float un = powf(av[t] / Kv, fi);
      if (it == M_REAL) rho_u = logf(un / u[t]);
      u[t] = un;
    }
    __syncthreads();
    // ---- v phase: K^T u ----
    {
      float sum = 0.f;
      #pragma unroll 4
      for (int j8 = 0; j8 < 32; j8++) {
        bf16x8 kv = *(const bf16x8*)(rowKT + j8 * 8);
        const float4* up = (const float4*)&u[half * 256 + j8 * 8];
        float4 u0 = up[0], u1 = up[1];
        sum += (float)kv[0] * u0.x + (float)kv[1] * u0.y + (float)kv[2] * u0.z +
               (float)kv[3] * u0.w + (float)kv[4] * u1.x + (float)kv[5] * u1.y +
               (float)kv[6] * u1.z + (float)kv[7] * u1.w;
      }
      part[t] = sum;
    }
    __syncthreads();
    if (t < 512) {
      float Ku = part[2 * t] + part[2 * t + 1];
      float vn = powf(bv[t] / Ku, fi);
      if (it == M_REAL) rho_v = logf(vn / v[t]);
      v[t] = vn;
    }
    __syncthreads();
  }

  // mean(rho_u), mean(rho_v) over 512
  part[t] = (t < 512) ? rho_u : 0.f;
  __syncthreads();
  for (int ofs = 512; ofs > 0; ofs >>= 1) {
    if (t < ofs) part[t] += part[t + ofs];
    __syncthreads();
  }
  if (t == 0) scal[0] = part[0] / 512.f;
  __syncthreads();
  part[t] = (t < 512) ? rho_v : 0.f;
  __syncthreads();
  for (int ofs = 512; ofs > 0; ofs >>= 1) {
    if (t < ofs) part[t] += part[t + ofs];
    __syncthreads();
  }
  if (t == 0) scal[1] = part[0] / 512.f;
  __syncthreads();

  // G = sum_{j=1}^{100-M_REAL} fi^(2j), computed in double for exactness
  double fi2d = (10.0 / 10.1) * (10.0 / 10.1);
  double Gd = 0.0, pd = 1.0;
  for (int j = 0; j < (N_TOT - M_REAL); j++) { pd *= fi2d; Gd += pd; }
  float Gf = (float)Gd;
  if (t < 512) {
    u_out[b * 512 + t] = u[t] * expf(Gf * scal[0]);
    v_out[b * 512 + t] = v[t] * expf(Gf * scal[1]);
  }
}

extern "C" void kernel_launch(void* const* d_in, const int* in_sizes, int n_in,
                              void* d_out, int out_size, void* d_ws, size_t ws_size,
                              hipStream_t stream) {
  (void)in_sizes; (void)n_in; (void)out_size; (void)ws_size;
  const float* src = (const float*)d_in[0];   // [32,512,1024]
  const float* tgt = (const float*)d_in[1];   // [32,512,1024]
  const int* smask = (const int*)d_in[2];     // [32,512]
  const int* gmask = (const int*)d_in[3];     // [32,512]
  const float* W   = (const float*)d_in[4];   // [1024,1024]
  const float* bias = (const float*)d_in[5];  // [1024]
  float* out = (float*)d_out;                 // [32,512,1024]

  uint8_t* ws = (uint8_t*)d_ws;
  bf16_t* s_bf  = (bf16_t*)(ws + 0);          // 33,554,432 B
  bf16_t* Kmat  = (bf16_t*)(ws + 0);          // reuse after gemm1: 16,777,216 B
  bf16_t* KTmat = (bf16_t*)(ws + 16777216);   // 16,777,216 B
  bf16_t* W_bf  = (bf16_t*)(ws + 33554432);   // 2,097,152 B
  bf16_t* g_bf  = (bf16_t*)(ws + 35651584);   // 33,554,432 B
  bf16_t* t_bf  = (bf16_t*)(ws + 69206016);   // 33,554,432 B
  bf16_t* gTv   = (bf16_t*)(ws + 69206016);   // reuse after gemm2
  float* s2  = (float*)(ws + 102760448);
  float* g2  = s2 + 16384;
  float* swv = g2 + 16384;
  float* gwv = swv + 16384;
  float* uv  = gwv + 16384;
  float* vv  = uv + 16384;

  // 1. conversions + g norms
  cvt_bf16_kernel<<<8192, 256, 0, stream>>>(src, s_bf, 2097152);
  cvt_bf16_kernel<<<512, 256, 0, stream>>>(W, W_bf, 131072);
  prep_g_kernel<<<16384, 128, 0, stream>>>(tgt, g_bf, g2);

  // 2. t = s @ W^T + b   (M=16384, N=1024, K=1024)
  gemm_bt_kernel<0><<<dim3(8, 128, 1), 256, 0, stream>>>(
      s_bf, W_bf, 1024, 0, 0, t_bf, 0, 1024, bias,
      nullptr, nullptr, nullptr, nullptr, nullptr);

  // 3. weights
  norm_t_kernel<<<16384, 128, 0, stream>>>(t_bf, s2);
  weights_kernel<<<32, 512, 0, stream>>>(s2, smask, swv);
  weights_kernel<<<32, 512, 0, stream>>>(g2, gmask, gwv);

  // 4. K = exp(-10*cost)  (per batch M=512, N=512, K=1024)
  gemm_bt_kernel<1><<<dim3(4, 4, 32), 256, 0, stream>>>(
      t_bf, g_bf, 1024, (size_t)512 * 1024, (size_t)512 * 1024,
      Kmat, (size_t)512 * 512, 512, nullptr, s2, g2, swv, gwv, nullptr);

  // 5. K^T
  transpose_k_kernel<<<dim3(16, 16, 32), 256, 0, stream>>>(Kmat, KTmat);

  // 6. Sinkhorn scalings
  sinkhorn_kernel<<<32, 1024, 0, stream>>>(Kmat, KTmat, swv, gwv, uv, vv);

  // 7. gTv[h][g] = v[g]*g[g][h]
  make_gtv_kernel<<<dim3(32, 16, 32), 256, 0, stream>>>(g_bf, vv, gTv);

  // 8. aligned = u .* (K @ gTv)   (per batch M=512, N=1024, K=512)
  gemm_bt_kernel<2><<<dim3(8, 4, 32), 256, 0, stream>>>(
      Kmat, gTv, 512, (size_t)512 * 512, (size_t)1024 * 512,
      out, (size_t)512 * 1024, 1024, nullptr, nullptr, nullptr, nullptr, nullptr, uv);
}

// Round 5
// 270.974 us; speedup vs baseline: 2.2306x; 2.2306x over previous
//
#include <hip/hip_runtime.h>
#include <hip/hip_bf16.h>
#include <math.h>

// EmbeddingAlignerOT on MI355X.
// Pipeline: cvt(s,W)->bf16 | prep_g(norm+cvt) | GEMM1 t=s@W^T+b (bf16 MFMA)
//   | norm_t | weights | GEMM2 K=exp(-cost*10) | transpose K |
//   sinkhorn: 4 real iterations as 8 grid-wide pass kernels + exact scalar
//   extrapolation to 100 | gTv=v*g^T | GEMM3 aligned = u.*(K @ gTv) -> fp32.
// Workspace layout (~103.2 MB):
//   [0, 32M)      s_bf16  -> reused as K (16M) + KT (16M) after gemm1
//   [32M, 34M)    W_bf16  -> reused as ua/ub/va/vb iterate buffers (4x64KB)
//   [34M, 66M)    g_bf16
//   [66M, 98M)    t_bf16  -> reused as gTv after gemm2
//   [98M, ...)    s2,g2,sw,gw,u,v (6 x 64KB fp32)

typedef __bf16 bf16_t;
typedef __bf16 bf16x8 __attribute__((ext_vector_type(8)));
typedef float  f32x4  __attribute__((ext_vector_type(4)));

#define NBATCH 32
#define NS 512
#define NG 512
#define NH 1024
#define M_REAL 4
#define N_TOT 100

__device__ __forceinline__ void async_copy16(const void* gsrc, void* ldst) {
  __builtin_amdgcn_global_load_lds(
      (__attribute__((address_space(1))) void*)gsrc,
      (__attribute__((address_space(3))) void*)ldst, 16, 0, 0);
}

// ---------- fp32 -> bf16 convert, 8 elems/thread ----------
__global__ __launch_bounds__(256) void cvt_bf16_kernel(const float* __restrict__ in,
                                                       bf16_t* __restrict__ out, int n8) {
  int i = blockIdx.x * 256 + threadIdx.x;
  if (i >= n8) return;
  const float4* p = (const float4*)in + (size_t)i * 2;
  float4 a = p[0], b = p[1];
  bf16x8 o;
  o[0] = (__bf16)a.x; o[1] = (__bf16)a.y; o[2] = (__bf16)a.z; o[3] = (__bf16)a.w;
  o[4] = (__bf16)b.x; o[5] = (__bf16)b.y; o[6] = (__bf16)b.z; o[7] = (__bf16)b.w;
  ((bf16x8*)out)[i] = o;
}

// ---------- target: convert to bf16 + fp32 row norms ----------
__global__ __launch_bounds__(128) void prep_g_kernel(const float* __restrict__ g,
                                                     bf16_t* __restrict__ gb,
                                                     float* __restrict__ g2) {
  int row = blockIdx.x;   // B*G rows of length NH
  int t = threadIdx.x;    // 128
  const float* rp = g + (size_t)row * NH + t * 8;
  float4 a = *(const float4*)rp;
  float4 b = *(const float4*)(rp + 4);
  bf16x8 o;
  o[0] = (__bf16)a.x; o[1] = (__bf16)a.y; o[2] = (__bf16)a.z; o[3] = (__bf16)a.w;
  o[4] = (__bf16)b.x; o[5] = (__bf16)b.y; o[6] = (__bf16)b.z; o[7] = (__bf16)b.w;
  ((bf16x8*)(gb + (size_t)row * NH))[t] = o;
  float ss = a.x*a.x + a.y*a.y + a.z*a.z + a.w*a.w
           + b.x*b.x + b.y*b.y + b.z*b.z + b.w*b.w;
  #pragma unroll
  for (int ofs = 32; ofs > 0; ofs >>= 1) ss += __shfl_down(ss, ofs);
  __shared__ float wsum[2];
  if ((t & 63) == 0) wsum[t >> 6] = ss;
  __syncthreads();
  if (t == 0) g2[row] = wsum[0] + wsum[1];
}

// ---------- row norms of bf16 t ----------
__global__ __launch_bounds__(128) void norm_t_kernel(const bf16_t* __restrict__ tb,
                                                     float* __restrict__ s2) {
  int row = blockIdx.x;
  int t = threadIdx.x;
  bf16x8 v = ((const bf16x8*)(tb + (size_t)row * NH))[t];
  float ss = 0.f;
  #pragma unroll
  for (int e = 0; e < 8; e++) { float f = (float)v[e]; ss += f * f; }
  #pragma unroll
  for (int ofs = 32; ofs > 0; ofs >>= 1) ss += __shfl_down(ss, ofs);
  __shared__ float wsum[2];
  if ((t & 63) == 0) wsum[t >> 6] = ss;
  __syncthreads();
  if (t == 0) s2[row] = wsum[0] + wsum[1];
}

// ---------- adjusted weights: w = mask*(sqrt(n2)+EPS)+EPS, normalized ----------
__global__ __launch_bounds__(512) void weights_kernel(const float* __restrict__ n2,
                                                      const int* __restrict__ mask,
                                                      float* __restrict__ wout) {
  int bb = blockIdx.x, t = threadIdx.x;
  int idx = bb * 512 + t;
  float mag = sqrtf(n2[idx]) + 1e-12f;
  float w = (float)mask[idx] * mag + 1e-12f;
  float ss = w;
  #pragma unroll
  for (int ofs = 32; ofs > 0; ofs >>= 1) ss += __shfl_down(ss, ofs);
  __shared__ float red[8];
  __shared__ float tot;
  if ((t & 63) == 0) red[t >> 6] = ss;
  __syncthreads();
  if (t == 0) {
    float x = 0.f;
    #pragma unroll
    for (int i = 0; i < 8; i++) x += red[i];
    tot = fmaxf(x, 1e-12f);
  }
  __syncthreads();
  wout[idx] = w / tot;
}

// ---------- C = A * B^T, 128x128 tile, BK=32, 4 waves, bf16 MFMA ----------
// MODE 0: t = A@B^T + bias, bf16 store           (gemm1)
// MODE 1: K = exp(-10*(sqrt(s2+g2-2C)*sw*gw+eps)) bf16 store (gemm2, batched)
// MODE 2: out = u .* C, fp32 store               (gemm3, batched)
template <int MODE>
__global__ __launch_bounds__(256) void gemm_bt_kernel(
    const bf16_t* __restrict__ A, const bf16_t* __restrict__ Bm, int K_len,
    size_t strideAb, size_t strideBb,
    void* __restrict__ outp, size_t strideOb, int ldc,
    const float* __restrict__ bias,
    const float* __restrict__ s2, const float* __restrict__ g2,
    const float* __restrict__ sw, const float* __restrict__ gw,
    const float* __restrict__ uvec) {
  __shared__ bf16_t lA[128 * 32];
  __shared__ bf16_t lB[128 * 32];
  const int tid = threadIdx.x, lane = tid & 63, wave = tid >> 6;
  const int wr = wave >> 1, wc = wave & 1;
  const int bz = blockIdx.z;
  const bf16_t* Ab = A + (size_t)bz * strideAb;
  const bf16_t* Bb = Bm + (size_t)bz * strideBb;
  const int m0 = blockIdx.y * 128, n0 = blockIdx.x * 128;
  const int rA = lane >> 2;       // row within 16-row staging group
  const int c8 = (lane & 3) * 8;  // bf16 col offset of this lane's 16B chunk

  f32x4 acc[4][4];
  #pragma unroll
  for (int i = 0; i < 4; i++)
    #pragma unroll
    for (int j = 0; j < 4; j++) { f32x4 z = {0.f, 0.f, 0.f, 0.f}; acc[i][j] = z; }

  for (int kt = 0; kt < K_len; kt += 32) {
    if (kt) __syncthreads();
    #pragma unroll
    for (int c = 0; c < 2; c++) {
      int rg = (c * 4 + wave) * 16;
      async_copy16(Ab + (size_t)(m0 + rg + rA) * K_len + kt + c8, &lA[rg * 32]);
      async_copy16(Bb + (size_t)(n0 + rg + rA) * K_len + kt + c8, &lB[rg * 32]);
    }
    __syncthreads();  // vmcnt(0) drained by compiler before barrier
    bf16x8 af[4], bf[4];
    #pragma unroll
    for (int m = 0; m < 4; m++)
      af[m] = *(const bf16x8*)&lA[(wr * 64 + m * 16 + (lane & 15)) * 32 + (lane >> 4) * 8];
    #pragma unroll
    for (int n = 0; n < 4; n++)
      bf[n] = *(const bf16x8*)&lB[(wc * 64 + n * 16 + (lane & 15)) * 32 + (lane >> 4) * 8];
    #pragma unroll
    for (int m = 0; m < 4; m++)
      #pragma unroll
      for (int n = 0; n < 4; n++)
        acc[m][n] = __builtin_amdgcn_mfma_f32_16x16x32_bf16(af[m], bf[n], acc[m][n], 0, 0, 0);
  }

  // epilogue: C/D frag mapping col=lane&15, row=(lane>>4)*4+j
  const int bo = bz * 512;
  const int row_base = m0 + wr * 64, col_base = n0 + wc * 64;
  const int r_off = (lane >> 4) * 4, c_off = lane & 15;
  #pragma unroll
  for (int m = 0; m < 4; m++) {
    #pragma unroll
    for (int n = 0; n < 4; n++) {
      #pragma unroll
      for (int j = 0; j < 4; j++) {
        int gm = row_base + m * 16 + r_off + j;
        int gn = col_base + n * 16 + c_off;
        float val = acc[m][n][j];
        if (MODE == 0) {
          ((bf16_t*)outp)[(size_t)gm * ldc + gn] = (__bf16)(val + bias[gn]);
        } else if (MODE == 1) {
          float sq = s2[bo + gm] + g2[bo + gn] - 2.0f * val;
          float d = sqrtf(fmaxf(sq, 0.0f));
          float cost = d * sw[bo + gm] * gw[bo + gn] + 1e-12f;
          ((bf16_t*)outp + (size_t)bz * strideOb)[(size_t)gm * ldc + gn] =
              (__bf16)expf(-10.0f * cost);
        } else {
          ((float*)outp + (size_t)bz * strideOb)[(size_t)gm * ldc + gn] =
              uvec[bo + gm] * val;
        }
      }
    }
  }
}

// ---------- K [S][G] -> KT [G][S] per batch ----------
__global__ __launch_bounds__(256) void transpose_k_kernel(const bf16_t* __restrict__ in,
                                                          bf16_t* __restrict__ out) {
  __shared__ bf16_t tl[32][33];
  size_t bo = (size_t)blockIdx.z * (NS * NG);
  int r0 = blockIdx.y * 32, c0 = blockIdx.x * 32;
  int tx = threadIdx.x & 31, ty = threadIdx.x >> 5;  // 8 rows/pass
  #pragma unroll
  for (int p = 0; p < 4; p++)
    tl[ty + p * 8][tx] = in[bo + (size_t)(r0 + ty + p * 8) * NG + c0 + tx];
  __syncthreads();
  #pragma unroll
  for (int p = 0; p < 4; p++)
    out[bo + (size_t)(c0 + ty + p * 8) * NS + r0 + tx] = tl[tx][ty + p * 8];
}

// ---------- gTv[h][g] = v[g] * g_bf[g][h] per batch ----------
__global__ __launch_bounds__(256) void make_gtv_kernel(const bf16_t* __restrict__ g,
                                                       const float* __restrict__ v,
                                                       bf16_t* __restrict__ out) {
  __shared__ bf16_t tl[32][33];
  size_t bi = (size_t)blockIdx.z * (NG * NH);
  int r0 = blockIdx.y * 32, c0 = blockIdx.x * 32;  // r over G, c over H
  int tx = threadIdx.x & 31, ty = threadIdx.x >> 5;
  #pragma unroll
  for (int p = 0; p < 4; p++)
    tl[ty + p * 8][tx] = g[bi + (size_t)(r0 + ty + p * 8) * NH + c0 + tx];
  __syncthreads();
  int vb = blockIdx.z * NG;
  #pragma unroll
  for (int p = 0; p < 4; p++) {
    int h = c0 + ty + p * 8, gg = r0 + tx;
    out[bi + (size_t)h * NG + gg] = (__bf16)((float)tl[tx][ty + p * 8] * v[vb + gg]);
  }
}

// ---------- Sinkhorn half-iteration, grid-wide ----------
// y[b][row] = (w[b][row] / dot(M[b][row][:], x[b][:]))^fi
// Grid: (NS/64, NBATCH), block 256 (4 threads per row, 64 rows/block).
// INIT=1: x is implicit uniform 1/512 (first u-pass).
// Lane-strided split (seg*8 + j*32) keeps LDS x reads conflict-free:
// same-seg lanes broadcast, distinct segs hit distinct bank groups.
template <int INIT>
__global__ __launch_bounds__(256) void sink_pass_kernel(
    const bf16_t* __restrict__ Mmat, const float* __restrict__ x,
    const float* __restrict__ w, float* __restrict__ y) {
  const int b = blockIdx.y;
  const int t = threadIdx.x;
  __shared__ float xs[512];
  if (!INIT) {
    ((float2*)xs)[t] = ((const float2*)(x + b * 512))[t];
    __syncthreads();
  }
  const int row = blockIdx.x * 64 + (t >> 2);
  const int seg = t & 3;
  const bf16_t* rp = Mmat + ((size_t)b * 512 + row) * 512;
  float sum = 0.f;
  #pragma unroll
  for (int j = 0; j < 16; j++) {
    bf16x8 kv = *(const bf16x8*)(rp + seg * 8 + j * 32);
    if (INIT) {
      sum += (float)kv[0] + (float)kv[1] + (float)kv[2] + (float)kv[3] +
             (float)kv[4] + (float)kv[5] + (float)kv[6] + (float)kv[7];
    } else {
      const float4* xp = (const float4*)&xs[seg * 8 + j * 32];
      float4 x0 = xp[0], x1 = xp[1];
      sum += (float)kv[0] * x0.x + (float)kv[1] * x0.y + (float)kv[2] * x0.z +
             (float)kv[3] * x0.w + (float)kv[4] * x1.x + (float)kv[5] * x1.y +
             (float)kv[6] * x1.z + (float)kv[7] * x1.w;
    }
  }
  if (INIT) sum *= (1.0f / 512.0f);
  sum += __shfl_xor(sum, 1);
  sum += __shfl_xor(sum, 2);
  if (seg == 0)
    y[b * 512 + row] = powf(w[b * 512 + row] / sum, 10.0f / 10.1f);
}

// ---------- Sinkhorn closed-form extrapolation to iteration 100 ----------
// rho = mean log(x_M / x_{M-1}); x_100 = x_M * exp(rho * sum_{j=1..100-M} fi^2j)
__global__ __launch_bounds__(512) void sink_final_kernel(
    const float* __restrict__ ua, const float* __restrict__ ub,
    const float* __restrict__ va, const float* __restrict__ vb,
    float* __restrict__ u_out, float* __restrict__ v_out, float Gf) {
  const int b = blockIdx.x, t = threadIdx.x, idx = b * 512 + t;
  const float ubv = ub[idx], vbv = vb[idx];
  float su = logf(ubv / ua[idx]);
  float sv = logf(vbv / va[idx]);
  #pragma unroll
  for (int ofs = 32; ofs > 0; ofs >>= 1) {
    su += __shfl_down(su, ofs);
    sv += __shfl_down(sv, ofs);
  }
  __shared__ float r0[8], r1[8];
  __shared__ float mu, mv;
  if ((t & 63) == 0) { r0[t >> 6] = su; r1[t >> 6] = sv; }
  __syncthreads();
  if (t == 0) {
    float a = 0.f, c = 0.f;
    #pragma unroll
    for (int i = 0; i < 8; i++) { a += r0[i]; c += r1[i]; }
    mu = a / 512.f; mv = c / 512.f;
  }
  __syncthreads();
  u_out[idx] = ubv * expf(Gf * mu);
  v_out[idx] = vbv * expf(Gf * mv);
}

extern "C" void kernel_launch(void* const* d_in, const int* in_sizes, int n_in,
                              void* d_out, int out_size, void* d_ws, size_t ws_size,
                              hipStream_t stream) {
  (void)in_sizes; (void)n_in; (void)out_size; (void)ws_size;
  const float* src = (const float*)d_in[0];   // [32,512,1024]
  const float* tgt = (const float*)d_in[1];   // [32,512,1024]
  const int* smask = (const int*)d_in[2];     // [32,512]
  const int* gmask = (const int*)d_in[3];     // [32,512]
  const float* W   = (const float*)d_in[4];   // [1024,1024]
  const float* bias = (const float*)d_in[5];  // [1024]
  float* out = (float*)d_out;                 // [32,512,1024]

  uint8_t* ws = (uint8_t*)d_ws;
  bf16_t* s_bf  = (bf16_t*)(ws + 0);          // 33,554,432 B
  bf16_t* Kmat  = (bf16_t*)(ws + 0);          // reuse after gemm1: 16,777,216 B
  bf16_t* KTmat = (bf16_t*)(ws + 16777216);   // 16,777,216 B
  bf16_t* W_bf  = (bf16_t*)(ws + 33554432);   // 2,097,152 B
  // iterate buffers overwrite W_bf once gemm1 is done (4 x 64 KB)
  float* ua = (float*)(ws + 33554432);
  float* ub = ua + 16384;
  float* va = ub + 16384;
  float* vb = va + 16384;
  bf16_t* g_bf  = (bf16_t*)(ws + 35651584);   // 33,554,432 B
  bf16_t* t_bf  = (bf16_t*)(ws + 69206016);   // 33,554,432 B
  bf16_t* gTv   = (bf16_t*)(ws + 69206016);   // reuse after gemm2
  float* s2  = (float*)(ws + 102760448);
  float* g2  = s2 + 16384;
  float* swv = g2 + 16384;
  float* gwv = swv + 16384;
  float* uv  = gwv + 16384;
  float* vv  = uv + 16384;

  // 1. conversions + g norms
  cvt_bf16_kernel<<<8192, 256, 0, stream>>>(src, s_bf, 2097152);
  cvt_bf16_kernel<<<512, 256, 0, stream>>>(W, W_bf, 131072);
  prep_g_kernel<<<16384, 128, 0, stream>>>(tgt, g_bf, g2);

  // 2. t = s @ W^T + b   (M=16384, N=1024, K=1024)
  gemm_bt_kernel<0><<<dim3(8, 128, 1), 256, 0, stream>>>(
      s_bf, W_bf, 1024, 0, 0, t_bf, 0, 1024, bias,
      nullptr, nullptr, nullptr, nullptr, nullptr);

  // 3. weights
  norm_t_kernel<<<16384, 128, 0, stream>>>(t_bf, s2);
  weights_kernel<<<32, 512, 0, stream>>>(s2, smask, swv);
  weights_kernel<<<32, 512, 0, stream>>>(g2, gmask, gwv);

  // 4. K = exp(-10*cost)  (per batch M=512, N=512, K=1024)
  gemm_bt_kernel<1><<<dim3(4, 4, 32), 256, 0, stream>>>(
      t_bf, g_bf, 1024, (size_t)512 * 1024, (size_t)512 * 1024,
      Kmat, (size_t)512 * 512, 512, nullptr, s2, g2, swv, gwv, nullptr);

  // 5. K^T
  transpose_k_kernel<<<dim3(16, 16, 32), 256, 0, stream>>>(Kmat, KTmat);

  // 6. Sinkhorn: 4 real iterations (8 grid-wide passes) + extrapolation.
  // u-iterates: u1->ua u2->ub u3->ua u4->ub; v likewise. Ratio pairs are
  // (ua,ub)=(u3,u4), (va,vb)=(v3,v4).
  dim3 pg(NS / 64, NBATCH);
  sink_pass_kernel<1><<<pg, 256, 0, stream>>>(Kmat, nullptr, swv, ua);   // u1
  sink_pass_kernel<0><<<pg, 256, 0, stream>>>(KTmat, ua, gwv, va);       // v1
  sink_pass_kernel<0><<<pg, 256, 0, stream>>>(Kmat, va, swv, ub);        // u2
  sink_pass_kernel<0><<<pg, 256, 0, stream>>>(KTmat, ub, gwv, vb);       // v2
  sink_pass_kernel<0><<<pg, 256, 0, stream>>>(Kmat, vb, swv, ua);        // u3
  sink_pass_kernel<0><<<pg, 256, 0, stream>>>(KTmat, ua, gwv, va);       // v3
  sink_pass_kernel<0><<<pg, 256, 0, stream>>>(Kmat, va, swv, ub);        // u4
  sink_pass_kernel<0><<<pg, 256, 0, stream>>>(KTmat, ub, gwv, vb);       // v4

  // G = sum_{j=1}^{100-M_REAL} fi^(2j) in double
  double fi2 = (10.0 / 10.1) * (10.0 / 10.1);
  double Gd = 0.0, pd = 1.0;
  for (int j = 0; j < (N_TOT - M_REAL); j++) { pd *= fi2; Gd += pd; }
  sink_final_kernel<<<32, 512, 0, stream>>>(ua, ub, va, vb, uv, vv, (float)Gd);

  // 7. gTv[h][g] = v[g]*g[g][h]
  make_gtv_kernel<<<dim3(32, 16, 32), 256, 0, stream>>>(g_bf, vv, gTv);

  // 8. aligned = u .* (K @ gTv)   (per batch M=512, N=1024, K=512)
  gemm_bt_kernel<2><<<dim3(8, 4, 32), 256, 0, stream>>>(
      Kmat, gTv, 512, (size_t)512 * 512, (size_t)1024 * 512,
      out, (size_t)512 * 1024, 1024, nullptr, nullptr, nullptr, nullptr, nullptr, uv);
}

// Round 6
// 248.121 us; speedup vs baseline: 2.4361x; 1.0921x over previous
//
#include <hip/hip_runtime.h>
#include <hip/hip_bf16.h>
#include <math.h>

// EmbeddingAlignerOT on MI355X.
// Pipeline: cvt(s,W)->bf16 | prep_g(norm+cvt) | GEMM1 t=s@W^T+b (bf16 MFMA)
//   | norm_t | weights | GEMM2 K=exp(-cost*10) | transpose K |
//   sinkhorn: 4 real iterations as 8 grid-wide pass kernels + exact scalar
//   extrapolation to 100 | gTv=v*g^T | GEMM3 aligned = u.*(K @ gTv) -> fp32.
// R6: XCD-aware bijective block swizzle on all 3 GEMMs (T1) — the 8/16/32
// blocks sharing an operand panel land on ONE XCD's L2 instead of 8.
// Workspace layout (~103.2 MB): see R2 comment.

typedef __bf16 bf16_t;
typedef __bf16 bf16x8 __attribute__((ext_vector_type(8)));
typedef float  f32x4  __attribute__((ext_vector_type(4)));

#define NBATCH 32
#define NS 512
#define NG 512
#define NH 1024
#define M_REAL 4
#define N_TOT 100

__device__ __forceinline__ void async_copy16(const void* gsrc, void* ldst) {
  __builtin_amdgcn_global_load_lds(
      (__attribute__((address_space(1))) void*)gsrc,
      (__attribute__((address_space(3))) void*)ldst, 16, 0, 0);
}

// ---------- fp32 -> bf16 convert, 8 elems/thread ----------
__global__ __launch_bounds__(256) void cvt_bf16_kernel(const float* __restrict__ in,
                                                       bf16_t* __restrict__ out, int n8) {
  int i = blockIdx.x * 256 + threadIdx.x;
  if (i >= n8) return;
  const float4* p = (const float4*)in + (size_t)i * 2;
  float4 a = p[0], b = p[1];
  bf16x8 o;
  o[0] = (__bf16)a.x; o[1] = (__bf16)a.y; o[2] = (__bf16)a.z; o[3] = (__bf16)a.w;
  o[4] = (__bf16)b.x; o[5] = (__bf16)b.y; o[6] = (__bf16)b.z; o[7] = (__bf16)b.w;
  ((bf16x8*)out)[i] = o;
}

// ---------- target: convert to bf16 + fp32 row norms ----------
__global__ __launch_bounds__(128) void prep_g_kernel(const float* __restrict__ g,
                                                     bf16_t* __restrict__ gb,
                                                     float* __restrict__ g2) {
  int row = blockIdx.x;   // B*G rows of length NH
  int t = threadIdx.x;    // 128
  const float* rp = g + (size_t)row * NH + t * 8;
  float4 a = *(const float4*)rp;
  float4 b = *(const float4*)(rp + 4);
  bf16x8 o;
  o[0] = (__bf16)a.x; o[1] = (__bf16)a.y; o[2] = (__bf16)a.z; o[3] = (__bf16)a.w;
  o[4] = (__bf16)b.x; o[5] = (__bf16)b.y; o[6] = (__bf16)b.z; o[7] = (__bf16)b.w;
  ((bf16x8*)(gb + (size_t)row * NH))[t] = o;
  float ss = a.x*a.x + a.y*a.y + a.z*a.z + a.w*a.w
           + b.x*b.x + b.y*b.y + b.z*b.z + b.w*b.w;
  #pragma unroll
  for (int ofs = 32; ofs > 0; ofs >>= 1) ss += __shfl_down(ss, ofs);
  __shared__ float wsum[2];
  if ((t & 63) == 0) wsum[t >> 6] = ss;
  __syncthreads();
  if (t == 0) g2[row] = wsum[0] + wsum[1];
}

// ---------- row norms of bf16 t ----------
__global__ __launch_bounds__(128) void norm_t_kernel(const bf16_t* __restrict__ tb,
                                                     float* __restrict__ s2) {
  int row = blockIdx.x;
  int t = threadIdx.x;
  bf16x8 v = ((const bf16x8*)(tb + (size_t)row * NH))[t];
  float ss = 0.f;
  #pragma unroll
  for (int e = 0; e < 8; e++) { float f = (float)v[e]; ss += f * f; }
  #pragma unroll
  for (int ofs = 32; ofs > 0; ofs >>= 1) ss += __shfl_down(ss, ofs);
  __shared__ float wsum[2];
  if ((t & 63) == 0) wsum[t >> 6] = ss;
  __syncthreads();
  if (t == 0) s2[row] = wsum[0] + wsum[1];
}

// ---------- adjusted weights for BOTH sides in one dispatch ----------
// blocks 0..31: source (s2,smask->swv); blocks 32..63: target (g2,gmask->gwv)
__global__ __launch_bounds__(512) void weights2_kernel(
    const float* __restrict__ s2, const int* __restrict__ smask, float* __restrict__ swv,
    const float* __restrict__ g2, const int* __restrict__ gmask, float* __restrict__ gwv) {
  int which = blockIdx.x >> 5;
  int bb = blockIdx.x & 31, t = threadIdx.x;
  const float* n2 = which ? g2 : s2;
  const int* mask = which ? gmask : smask;
  float* wout = which ? gwv : swv;
  int idx = bb * 512 + t;
  float mag = sqrtf(n2[idx]) + 1e-12f;
  float w = (float)mask[idx] * mag + 1e-12f;
  float ss = w;
  #pragma unroll
  for (int ofs = 32; ofs > 0; ofs >>= 1) ss += __shfl_down(ss, ofs);
  __shared__ float red[8];
  __shared__ float tot;
  if ((t & 63) == 0) red[t >> 6] = ss;
  __syncthreads();
  if (t == 0) {
    float x = 0.f;
    #pragma unroll
    for (int i = 0; i < 8; i++) x += red[i];
    tot = fmaxf(x, 1e-12f);
  }
  __syncthreads();
  wout[idx] = w / tot;
}

// ---------- C = A * B^T, 128x128 tile, BK=32, 4 waves, bf16 MFMA ----------
// 1-D grid, XCD-aware swizzle: hardware block L runs on XCD ~L%8; remap
// lin2=(L&7)*(nwg/8)+L>>3 gives each XCD a contiguous logical range, so all
// blocks sharing an operand panel hit one L2. Decompose x-fastest (GX,GY
// compile-time): GEMM1 16 row-panels/XCD, GEMM2/3 4 whole batches/XCD.
// MODE 0: t = A@B^T + bias, bf16 store           (gemm1)
// MODE 1: K = exp(-10*(sqrt(s2+g2-2C)*sw*gw+eps)) bf16 store (gemm2, batched)
// MODE 2: out = u .* C, fp32 store               (gemm3, batched)
template <int MODE, int GX, int GY>
__global__ __launch_bounds__(256) void gemm_bt_kernel(
    const bf16_t* __restrict__ A, const bf16_t* __restrict__ Bm, int K_len,
    size_t strideAb, size_t strideBb,
    void* __restrict__ outp, size_t strideOb, int ldc,
    const float* __restrict__ bias,
    const float* __restrict__ s2, const float* __restrict__ g2,
    const float* __restrict__ sw, const float* __restrict__ gw,
    const float* __restrict__ uvec) {
  __shared__ bf16_t lA[128 * 32];
  __shared__ bf16_t lB[128 * 32];
  const int nwg = gridDim.x;
  const int lin = blockIdx.x;
  const int lin2 = (lin & 7) * (nwg >> 3) + (lin >> 3);
  const int bx = lin2 % GX;
  const int by = (lin2 / GX) % GY;
  const int bz = lin2 / (GX * GY);
  const int tid = threadIdx.x, lane = tid & 63, wave = tid >> 6;
  const int wr = wave >> 1, wc = wave & 1;
  const bf16_t* Ab = A + (size_t)bz * strideAb;
  const bf16_t* Bb = Bm + (size_t)bz * strideBb;
  const int m0 = by * 128, n0 = bx * 128;
  const int rA = lane >> 2;       // row within 16-row staging group
  const int c8 = (lane & 3) * 8;  // bf16 col offset of this lane's 16B chunk

  f32x4 acc[4][4];
  #pragma unroll
  for (int i = 0; i < 4; i++)
    #pragma unroll
    for (int j = 0; j < 4; j++) { f32x4 z = {0.f, 0.f, 0.f, 0.f}; acc[i][j] = z; }

  for (int kt = 0; kt < K_len; kt += 32) {
    if (kt) __syncthreads();
    #pragma unroll
    for (int c = 0; c < 2; c++) {
      int rg = (c * 4 + wave) * 16;
      async_copy16(Ab + (size_t)(m0 + rg + rA) * K_len + kt + c8, &lA[rg * 32]);
      async_copy16(Bb + (size_t)(n0 + rg + rA) * K_len + kt + c8, &lB[rg * 32]);
    }
    __syncthreads();  // vmcnt(0) drained by compiler before barrier
    bf16x8 af[4], bf[4];
    #pragma unroll
    for (int m = 0; m < 4; m++)
      af[m] = *(const bf16x8*)&lA[(wr * 64 + m * 16 + (lane & 15)) * 32 + (lane >> 4) * 8];
    #pragma unroll
    for (int n = 0; n < 4; n++)
      bf[n] = *(const bf16x8*)&lB[(wc * 64 + n * 16 + (lane & 15)) * 32 + (lane >> 4) * 8];
    #pragma unroll
    for (int m = 0; m < 4; m++)
      #pragma unroll
      for (int n = 0; n < 4; n++)
        acc[m][n] = __builtin_amdgcn_mfma_f32_16x16x32_bf16(af[m], bf[n], acc[m][n], 0, 0, 0);
  }

  // epilogue: C/D frag mapping col=lane&15, row=(lane>>4)*4+j
  const int bo = bz * 512;
  const int row_base = m0 + wr * 64, col_base = n0 + wc * 64;
  const int r_off = (lane >> 4) * 4, c_off = lane & 15;
  #pragma unroll
  for (int m = 0; m < 4; m++) {
    #pragma unroll
    for (int n = 0; n < 4; n++) {
      #pragma unroll
      for (int j = 0; j < 4; j++) {
        int gm = row_base + m * 16 + r_off + j;
        int gn = col_base + n * 16 + c_off;
        float val = acc[m][n][j];
        if (MODE == 0) {
          ((bf16_t*)outp)[(size_t)gm * ldc + gn] = (__bf16)(val + bias[gn]);
        } else if (MODE == 1) {
          float sq = s2[bo + gm] + g2[bo + gn] - 2.0f * val;
          float d = sqrtf(fmaxf(sq, 0.0f));
          float cost = d * sw[bo + gm] * gw[bo + gn] + 1e-12f;
          ((bf16_t*)outp + (size_t)bz * strideOb)[(size_t)gm * ldc + gn] =
              (__bf16)expf(-10.0f * cost);
        } else {
          ((float*)outp + (size_t)bz * strideOb)[(size_t)gm * ldc + gn] =
              uvec[bo + gm] * val;
        }
      }
    }
  }
}

// ---------- K [S][G] -> KT [G][S] per batch ----------
__global__ __launch_bounds__(256) void transpose_k_kernel(const bf16_t* __restrict__ in,
                                                          bf16_t* __restrict__ out) {
  __shared__ bf16_t tl[32][33];
  size_t bo = (size_t)blockIdx.z * (NS * NG);
  int r0 = blockIdx.y * 32, c0 = blockIdx.x * 32;
  int tx = threadIdx.x & 31, ty = threadIdx.x >> 5;  // 8 rows/pass
  #pragma unroll
  for (int p = 0; p < 4; p++)
    tl[ty + p * 8][tx] = in[bo + (size_t)(r0 + ty + p * 8) * NG + c0 + tx];
  __syncthreads();
  #pragma unroll
  for (int p = 0; p < 4; p++)
    out[bo + (size_t)(c0 + ty + p * 8) * NS + r0 + tx] = tl[tx][ty + p * 8];
}

// ---------- gTv[h][g] = v[g] * g_bf[g][h] per batch ----------
__global__ __launch_bounds__(256) void make_gtv_kernel(const bf16_t* __restrict__ g,
                                                       const float* __restrict__ v,
                                                       bf16_t* __restrict__ out) {
  __shared__ bf16_t tl[32][33];
  size_t bi = (size_t)blockIdx.z * (NG * NH);
  int r0 = blockIdx.y * 32, c0 = blockIdx.x * 32;  // r over G, c over H
  int tx = threadIdx.x & 31, ty = threadIdx.x >> 5;
  #pragma unroll
  for (int p = 0; p < 4; p++)
    tl[ty + p * 8][tx] = g[bi + (size_t)(r0 + ty + p * 8) * NH + c0 + tx];
  __syncthreads();
  int vb = blockIdx.z * NG;
  #pragma unroll
  for (int p = 0; p < 4; p++) {
    int h = c0 + ty + p * 8, gg = r0 + tx;
    out[bi + (size_t)h * NG + gg] = (__bf16)((float)tl[tx][ty + p * 8] * v[vb + gg]);
  }
}

// ---------- Sinkhorn half-iteration, grid-wide ----------
// y[b][row] = (w[b][row] / dot(M[b][row][:], x[b][:]))^fi
// Grid: (NS/64, NBATCH), block 256 (4 threads per row, 64 rows/block).
template <int INIT>
__global__ __launch_bounds__(256) void sink_pass_kernel(
    const bf16_t* __restrict__ Mmat, const float* __restrict__ x,
    const float* __restrict__ w, float* __restrict__ y) {
  const int b = blockIdx.y;
  const int t = threadIdx.x;
  __shared__ float xs[512];
  if (!INIT) {
    ((float2*)xs)[t] = ((const float2*)(x + b * 512))[t];
    __syncthreads();
  }
  const int row = blockIdx.x * 64 + (t >> 2);
  const int seg = t & 3;
  const bf16_t* rp = Mmat + ((size_t)b * 512 + row) * 512;
  float sum = 0.f;
  #pragma unroll
  for (int j = 0; j < 16; j++) {
    bf16x8 kv = *(const bf16x8*)(rp + seg * 8 + j * 32);
    if (INIT) {
      sum += (float)kv[0] + (float)kv[1] + (float)kv[2] + (float)kv[3] +
             (float)kv[4] + (float)kv[5] + (float)kv[6] + (float)kv[7];
    } else {
      const float4* xp = (const float4*)&xs[seg * 8 + j * 32];
      float4 x0 = xp[0], x1 = xp[1];
      sum += (float)kv[0] * x0.x + (float)kv[1] * x0.y + (float)kv[2] * x0.z +
             (float)kv[3] * x0.w + (float)kv[4] * x1.x + (float)kv[5] * x1.y +
             (float)kv[6] * x1.z + (float)kv[7] * x1.w;
    }
  }
  if (INIT) sum *= (1.0f / 512.0f);
  sum += __shfl_xor(sum, 1);
  sum += __shfl_xor(sum, 2);
  if (seg == 0)
    y[b * 512 + row] = powf(w[b * 512 + row] / sum, 10.0f / 10.1f);
}

// ---------- Sinkhorn closed-form extrapolation to iteration 100 ----------
// rho = mean log(x_M / x_{M-1}); x_100 = x_M * exp(rho * sum_{j=1..100-M} fi^2j)
__global__ __launch_bounds__(512) void sink_final_kernel(
    const float* __restrict__ ua, const float* __restrict__ ub,
    const float* __restrict__ va, const float* __restrict__ vb,
    float* __restrict__ u_out, float* __restrict__ v_out, float Gf) {
  const int b = blockIdx.x, t = threadIdx.x, idx = b * 512 + t;
  const float ubv = ub[idx], vbv = vb[idx];
  float su = logf(ubv / ua[idx]);
  float sv = logf(vbv / va[idx]);
  #pragma unroll
  for (int ofs = 32; ofs > 0; ofs >>= 1) {
    su += __shfl_down(su, ofs);
    sv += __shfl_down(sv, ofs);
  }
  __shared__ float r0[8], r1[8];
  __shared__ float mu, mv;
  if ((t & 63) == 0) { r0[t >> 6] = su; r1[t >> 6] = sv; }
  __syncthreads();
  if (t == 0) {
    float a = 0.f, c = 0.f;
    #pragma unroll
    for (int i = 0; i < 8; i++) { a += r0[i]; c += r1[i]; }
    mu = a / 512.f; mv = c / 512.f;
  }
  __syncthreads();
  u_out[idx] = ubv * expf(Gf * mu);
  v_out[idx] = vbv * expf(Gf * mv);
}

extern "C" void kernel_launch(void* const* d_in, const int* in_sizes, int n_in,
                              void* d_out, int out_size, void* d_ws, size_t ws_size,
                              hipStream_t stream) {
  (void)in_sizes; (void)n_in; (void)out_size; (void)ws_size;
  const float* src = (const float*)d_in[0];   // [32,512,1024]
  const float* tgt = (const float*)d_in[1];   // [32,512,1024]
  const int* smask = (const int*)d_in[2];     // [32,512]
  const int* gmask = (const int*)d_in[3];     // [32,512]
  const float* W   = (const float*)d_in[4];   // [1024,1024]
  const float* bias = (const float*)d_in[5];  // [1024]
  float* out = (float*)d_out;                 // [32,512,1024]

  uint8_t* ws = (uint8_t*)d_ws;
  bf16_t* s_bf  = (bf16_t*)(ws + 0);          // 33,554,432 B
  bf16_t* Kmat  = (bf16_t*)(ws + 0);          // reuse after gemm1: 16,777,216 B
  bf16_t* KTmat = (bf16_t*)(ws + 16777216);   // 16,777,216 B
  bf16_t* W_bf  = (bf16_t*)(ws + 33554432);   // 2,097,152 B
  // iterate buffers overwrite W_bf once gemm1 is done (4 x 64 KB)
  float* ua = (float*)(ws + 33554432);
  float* ub = ua + 16384;
  float* va = ub + 16384;
  float* vb = va + 16384;
  bf16_t* g_bf  = (bf16_t*)(ws + 35651584);   // 33,554,432 B
  bf16_t* t_bf  = (bf16_t*)(ws + 69206016);   // 33,554,432 B
  bf16_t* gTv   = (bf16_t*)(ws + 69206016);   // reuse after gemm2
  float* s2  = (float*)(ws + 102760448);
  float* g2  = s2 + 16384;
  float* swv = g2 + 16384;
  float* gwv = swv + 16384;
  float* uv  = gwv + 16384;
  float* vv  = uv + 16384;

  // 1. conversions + g norms
  cvt_bf16_kernel<<<8192, 256, 0, stream>>>(src, s_bf, 2097152);
  cvt_bf16_kernel<<<512, 256, 0, stream>>>(W, W_bf, 131072);
  prep_g_kernel<<<16384, 128, 0, stream>>>(tgt, g_bf, g2);

  // 2. t = s @ W^T + b   (M=16384, N=1024, K=1024), 1024 blocks, XCD-swizzled
  gemm_bt_kernel<0, 8, 128><<<1024, 256, 0, stream>>>(
      s_bf, W_bf, 1024, 0, 0, t_bf, 0, 1024, bias,
      nullptr, nullptr, nullptr, nullptr, nullptr);

  // 3. weights (row norms of t, then both normalizations in one dispatch)
  norm_t_kernel<<<16384, 128, 0, stream>>>(t_bf, s2);
  weights2_kernel<<<64, 512, 0, stream>>>(s2, smask, swv, g2, gmask, gwv);

  // 4. K = exp(-10*cost)  (per batch M=512, N=512, K=1024), 512 blocks
  gemm_bt_kernel<1, 4, 4><<<512, 256, 0, stream>>>(
      t_bf, g_bf, 1024, (size_t)512 * 1024, (size_t)512 * 1024,
      Kmat, (size_t)512 * 512, 512, nullptr, s2, g2, swv, gwv, nullptr);

  // 5. K^T
  transpose_k_kernel<<<dim3(16, 16, 32), 256, 0, stream>>>(Kmat, KTmat);

  // 6. Sinkhorn: 4 real iterations (8 grid-wide passes) + extrapolation.
  dim3 pg(NS / 64, NBATCH);
  sink_pass_kernel<1><<<pg, 256, 0, stream>>>(Kmat, nullptr, swv, ua);   // u1
  sink_pass_kernel<0><<<pg, 256, 0, stream>>>(KTmat, ua, gwv, va);       // v1
  sink_pass_kernel<0><<<pg, 256, 0, stream>>>(Kmat, va, swv, ub);        // u2
  sink_pass_kernel<0><<<pg, 256, 0, stream>>>(KTmat, ub, gwv, vb);       // v2
  sink_pass_kernel<0><<<pg, 256, 0, stream>>>(Kmat, vb, swv, ua);        // u3
  sink_pass_kernel<0><<<pg, 256, 0, stream>>>(KTmat, ua, gwv, va);       // v3
  sink_pass_kernel<0><<<pg, 256, 0, stream>>>(Kmat, va, swv, ub);        // u4
  sink_pass_kernel<0><<<pg, 256, 0, stream>>>(KTmat, ub, gwv, vb);       // v4

  // G = sum_{j=1}^{100-M_REAL} fi^(2j) in double
  double fi2 = (10.0 / 10.1) * (10.0 / 10.1);
  double Gd = 0.0, pd = 1.0;
  for (int j = 0; j < (N_TOT - M_REAL); j++) { pd *= fi2; Gd += pd; }
  sink_final_kernel<<<32, 512, 0, stream>>>(ua, ub, va, vb, uv, vv, (float)Gd);

  // 7. gTv[h][g] = v[g]*g[g][h]
  make_gtv_kernel<<<dim3(32, 16, 32), 256, 0, stream>>>(g_bf, vv, gTv);

  // 8. aligned = u .* (K @ gTv)   (per batch M=512, N=1024, K=512), 1024 blocks
  gemm_bt_kernel<2, 8, 4><<<1024, 256, 0, stream>>>(
      Kmat, gTv, 512, (size_t)512 * 512, (size_t)1024 * 512,
      out, (size_t)512 * 1024, 1024, nullptr, nullptr, nullptr, nullptr, nullptr, uv);
}

// Round 7
// 222.058 us; speedup vs baseline: 2.7220x; 1.1174x over previous
//
#include <hip/hip_runtime.h>
#include <hip/hip_bf16.h>
#include <math.h>

// EmbeddingAlignerOT on MI355X.
// R7: BK=64 GEMMs (halve barrier drains), norm_t fused into GEMM1 epilogue
// (atomics into zeroed s2), M_REAL=3 (6 sink passes), wide transpose template
// for KT and gTv, merged cvt dispatch.
// Workspace (~103.2 MB): [0,32M) s_bf -> K+KT after gemm1 | [32M,34M) W_bf ->
// ua/ub/va/vb | [34M,66M) g_bf | [66M,98M) t_bf -> gTv | [98M..) s2,g2,sw,gw,u,v

typedef __bf16 bf16_t;
typedef __bf16 bf16x8 __attribute__((ext_vector_type(8)));
typedef float  f32x4  __attribute__((ext_vector_type(4)));

#define NBATCH 32
#define NS 512
#define NG 512
#define NH 1024
#define M_REAL 3
#define N_TOT 100

__device__ __forceinline__ void async_copy16(const void* gsrc, void* ldst) {
  __builtin_amdgcn_global_load_lds(
      (__attribute__((address_space(1))) void*)gsrc,
      (__attribute__((address_space(3))) void*)ldst, 16, 0, 0);
}

// ---------- fp32 -> bf16 convert, src and W in one dispatch ----------
__global__ __launch_bounds__(256) void cvt2_kernel(const float* __restrict__ a,
                                                   bf16_t* __restrict__ outa, int n8a,
                                                   const float* __restrict__ b,
                                                   bf16_t* __restrict__ outb) {
  int i = blockIdx.x * 256 + threadIdx.x;
  const float* src;
  bf16_t* dst;
  int idx;
  if (i < n8a) { src = a; dst = outa; idx = i; }
  else         { src = b; dst = outb; idx = i - n8a; }
  const float4* p = (const float4*)src + (size_t)idx * 2;
  float4 x = p[0], y = p[1];
  bf16x8 o;
  o[0] = (__bf16)x.x; o[1] = (__bf16)x.y; o[2] = (__bf16)x.z; o[3] = (__bf16)x.w;
  o[4] = (__bf16)y.x; o[5] = (__bf16)y.y; o[6] = (__bf16)y.z; o[7] = (__bf16)y.w;
  ((bf16x8*)dst)[idx] = o;
}

// ---------- target: convert to bf16 + fp32 row norms ----------
__global__ __launch_bounds__(128) void prep_g_kernel(const float* __restrict__ g,
                                                     bf16_t* __restrict__ gb,
                                                     float* __restrict__ g2) {
  int row = blockIdx.x;   // B*G rows of length NH
  int t = threadIdx.x;    // 128
  const float* rp = g + (size_t)row * NH + t * 8;
  float4 a = *(const float4*)rp;
  float4 b = *(const float4*)(rp + 4);
  bf16x8 o;
  o[0] = (__bf16)a.x; o[1] = (__bf16)a.y; o[2] = (__bf16)a.z; o[3] = (__bf16)a.w;
  o[4] = (__bf16)b.x; o[5] = (__bf16)b.y; o[6] = (__bf16)b.z; o[7] = (__bf16)b.w;
  ((bf16x8*)(gb + (size_t)row * NH))[t] = o;
  float ss = a.x*a.x + a.y*a.y + a.z*a.z + a.w*a.w
           + b.x*b.x + b.y*b.y + b.z*b.z + b.w*b.w;
  #pragma unroll
  for (int ofs = 32; ofs > 0; ofs >>= 1) ss += __shfl_down(ss, ofs);
  __shared__ float wsum[2];
  if ((t & 63) == 0) wsum[t >> 6] = ss;
  __syncthreads();
  if (t == 0) g2[row] = wsum[0] + wsum[1];
}

// ---------- adjusted weights for BOTH sides in one dispatch ----------
__global__ __launch_bounds__(512) void weights2_kernel(
    const float* __restrict__ s2, const int* __restrict__ smask, float* __restrict__ swv,
    const float* __restrict__ g2, const int* __restrict__ gmask, float* __restrict__ gwv) {
  int which = blockIdx.x >> 5;
  int bb = blockIdx.x & 31, t = threadIdx.x;
  const float* n2 = which ? g2 : s2;
  const int* mask = which ? gmask : smask;
  float* wout = which ? gwv : swv;
  int idx = bb * 512 + t;
  float mag = sqrtf(n2[idx]) + 1e-12f;
  float w = (float)mask[idx] * mag + 1e-12f;
  float ss = w;
  #pragma unroll
  for (int ofs = 32; ofs > 0; ofs >>= 1) ss += __shfl_down(ss, ofs);
  __shared__ float red[8];
  __shared__ float tot;
  if ((t & 63) == 0) red[t >> 6] = ss;
  __syncthreads();
  if (t == 0) {
    float x = 0.f;
    #pragma unroll
    for (int i = 0; i < 8; i++) x += red[i];
    tot = fmaxf(x, 1e-12f);
  }
  __syncthreads();
  wout[idx] = w / tot;
}

// ---------- C = A * B^T, 128x128 tile, BK=64, 4 waves, bf16 MFMA ----------
// XCD-aware bijective swizzle (1-D grid, nwg%8==0).
// MODE 0: t = A@B^T + bias, bf16 store; fused row-norm atomicAdd into s2arg
// MODE 1: K = exp(-10*(sqrt(s2+g2-2C)*sw*gw+eps)) bf16 store (batched)
// MODE 2: out = u .* C, fp32 store (batched)
template <int MODE, int GX, int GY>
__global__ __launch_bounds__(256) void gemm_bt_kernel(
    const bf16_t* __restrict__ A, const bf16_t* __restrict__ Bm, int K_len,
    size_t strideAb, size_t strideBb,
    void* __restrict__ outp, size_t strideOb, int ldc,
    const float* __restrict__ bias,
    const float* __restrict__ s2, const float* __restrict__ g2,
    const float* __restrict__ sw, const float* __restrict__ gw,
    const float* __restrict__ uvec, float* __restrict__ s2out) {
  __shared__ bf16_t lA[128 * 64];
  __shared__ bf16_t lB[128 * 64];
  const int nwg = gridDim.x;
  const int lin = blockIdx.x;
  const int lin2 = (lin & 7) * (nwg >> 3) + (lin >> 3);
  const int bx = lin2 % GX;
  const int by = (lin2 / GX) % GY;
  const int bz = lin2 / (GX * GY);
  const int tid = threadIdx.x, lane = tid & 63, wave = tid >> 6;
  const int wr = wave >> 1, wc = wave & 1;
  const bf16_t* Ab = A + (size_t)bz * strideAb;
  const bf16_t* Bb = Bm + (size_t)bz * strideBb;
  const int m0 = by * 128, n0 = bx * 128;
  const int rA = lane >> 3;       // row within 8-row staging group
  const int c8 = (lane & 7) * 8;  // bf16 col offset of this lane's 16B chunk

  f32x4 acc[4][4];
  #pragma unroll
  for (int i = 0; i < 4; i++)
    #pragma unroll
    for (int j = 0; j < 4; j++) { f32x4 z = {0.f, 0.f, 0.f, 0.f}; acc[i][j] = z; }

  for (int kt = 0; kt < K_len; kt += 64) {
    if (kt) __syncthreads();
    #pragma unroll
    for (int c = 0; c < 4; c++) {
      int rg = (c * 4 + wave) * 8;   // 16 groups of 8 rows
      async_copy16(Ab + (size_t)(m0 + rg + rA) * K_len + kt + c8, &lA[rg * 64]);
      async_copy16(Bb + (size_t)(n0 + rg + rA) * K_len + kt + c8, &lB[rg * 64]);
    }
    __syncthreads();  // compiler drains vmcnt(0) before barrier
    #pragma unroll
    for (int kk = 0; kk < 2; kk++) {
      bf16x8 af[4], bf[4];
      #pragma unroll
      for (int m = 0; m < 4; m++)
        af[m] = *(const bf16x8*)&lA[(wr * 64 + m * 16 + (lane & 15)) * 64 +
                                    kk * 32 + (lane >> 4) * 8];
      #pragma unroll
      for (int n = 0; n < 4; n++)
        bf[n] = *(const bf16x8*)&lB[(wc * 64 + n * 16 + (lane & 15)) * 64 +
                                    kk * 32 + (lane >> 4) * 8];
      #pragma unroll
      for (int m = 0; m < 4; m++)
        #pragma unroll
        for (int n = 0; n < 4; n++)
          acc[m][n] = __builtin_amdgcn_mfma_f32_16x16x32_bf16(af[m], bf[n], acc[m][n], 0, 0, 0);
    }
  }

  // epilogue: C/D frag mapping col=lane&15, row=(lane>>4)*4+j
  const int bo = bz * 512;
  const int row_base = m0 + wr * 64, col_base = n0 + wc * 64;
  const int r_off = (lane >> 4) * 4, c_off = lane & 15;
  float p[4][4];   // MODE0: per-thread row partial sums of (val+bias)^2
  #pragma unroll
  for (int m = 0; m < 4; m++)
    #pragma unroll
    for (int j = 0; j < 4; j++) p[m][j] = 0.f;

  #pragma unroll
  for (int m = 0; m < 4; m++) {
    #pragma unroll
    for (int n = 0; n < 4; n++) {
      #pragma unroll
      for (int j = 0; j < 4; j++) {
        int gm = row_base + m * 16 + r_off + j;
        int gn = col_base + n * 16 + c_off;
        float val = acc[m][n][j];
        if (MODE == 0) {
          float tv = val + bias[gn];
          ((bf16_t*)outp)[(size_t)gm * ldc + gn] = (__bf16)tv;
          p[m][j] += tv * tv;
        } else if (MODE == 1) {
          float sq = s2[bo + gm] + g2[bo + gn] - 2.0f * val;
          float d = sqrtf(fmaxf(sq, 0.0f));
          float cost = d * sw[bo + gm] * gw[bo + gn] + 1e-12f;
          ((bf16_t*)outp + (size_t)bz * strideOb)[(size_t)gm * ldc + gn] =
              (__bf16)expf(-10.0f * cost);
        } else {
          ((float*)outp + (size_t)bz * strideOb)[(size_t)gm * ldc + gn] =
              uvec[bo + gm] * val;
        }
      }
    }
  }

  if (MODE == 0) {
    // reduce (val+bias)^2 across the 128 cols this block owns, atomicAdd to s2out
    __syncthreads();               // all LDS reads done; reuse lA
    float* lRed = (float*)lA;      // 128 floats
    #pragma unroll
    for (int m = 0; m < 4; m++)
      #pragma unroll
      for (int j = 0; j < 4; j++) {
        float v = p[m][j];
        v += __shfl_xor(v, 1);
        v += __shfl_xor(v, 2);
        v += __shfl_xor(v, 4);
        v += __shfl_xor(v, 8);
        p[m][j] = v;               // valid at lanes with (lane&15)==0
      }
    int rl = wr * 64 + (lane >> 4) * 4;
    if (wc == 0 && (lane & 15) == 0) {
      #pragma unroll
      for (int m = 0; m < 4; m++)
        #pragma unroll
        for (int j = 0; j < 4; j++) lRed[rl + m * 16 + j] = p[m][j];
    }
    __syncthreads();
    if (wc == 1 && (lane & 15) == 0) {
      #pragma unroll
      for (int m = 0; m < 4; m++)
        #pragma unroll
        for (int j = 0; j < 4; j++)
          atomicAdd(&s2out[m0 + rl + m * 16 + j], lRed[rl + m * 16 + j] + p[m][j]);
    }
  }
}

// ---------- wide transpose: out[c][r] = in[r][c] * (SCALE ? v[r] : 1) ----------
// grid (inCols/64, inRows/32, NBATCH), block 256. 16B global accesses both sides.
template <int SCALE>
__global__ __launch_bounds__(256) void wide_transpose_kernel(
    const bf16_t* __restrict__ in, bf16_t* __restrict__ out,
    const float* __restrict__ vscale, int inRows, int inCols) {
  __shared__ bf16_t tl[32][66];   // pad 66: rq-groups land on distinct banks
  size_t base = (size_t)blockIdx.z * inRows * inCols;
  int r0 = blockIdx.y * 32, c0 = blockIdx.x * 64;
  int row = threadIdx.x >> 3, cc8 = (threadIdx.x & 7) * 8;
  *(bf16x8*)&tl[row][cc8] =
      *(const bf16x8*)(in + base + (size_t)(r0 + row) * inCols + c0 + cc8);
  __syncthreads();
  int orow = threadIdx.x >> 2;       // 0..63 : output row (= input col)
  int rq = (threadIdx.x & 3) * 8;    // 0,8,16,24 : input-row chunk
  bf16x8 o;
  if (SCALE) {
    const float* vp = vscale + (size_t)blockIdx.z * inRows + r0 + rq;
    float4 va = *(const float4*)vp;
    float4 vb = *(const float4*)(vp + 4);
    o[0] = (__bf16)((float)tl[rq + 0][orow] * va.x);
    o[1] = (__bf16)((float)tl[rq + 1][orow] * va.y);
    o[2] = (__bf16)((float)tl[rq + 2][orow] * va.z);
    o[3] = (__bf16)((float)tl[rq + 3][orow] * va.w);
    o[4] = (__bf16)((float)tl[rq + 4][orow] * vb.x);
    o[5] = (__bf16)((float)tl[rq + 5][orow] * vb.y);
    o[6] = (__bf16)((float)tl[rq + 6][orow] * vb.z);
    o[7] = (__bf16)((float)tl[rq + 7][orow] * vb.w);
  } else {
    #pragma unroll
    for (int i = 0; i < 8; i++) o[i] = tl[rq + i][orow];
  }
  *(bf16x8*)(out + base + (size_t)(c0 + orow) * inRows + r0 + rq) = o;
}

// ---------- Sinkhorn half-iteration, grid-wide ----------
template <int INIT>
__global__ __launch_bounds__(256) void sink_pass_kernel(
    const bf16_t* __restrict__ Mmat, const float* __restrict__ x,
    const float* __restrict__ w, float* __restrict__ y) {
  const int b = blockIdx.y;
  const int t = threadIdx.x;
  __shared__ float xs[512];
  if (!INIT) {
    ((float2*)xs)[t] = ((const float2*)(x + b * 512))[t];
    __syncthreads();
  }
  const int row = blockIdx.x * 64 + (t >> 2);
  const int seg = t & 3;
  const bf16_t* rp = Mmat + ((size_t)b * 512 + row) * 512;
  float sum = 0.f;
  #pragma unroll
  for (int j = 0; j < 16; j++) {
    bf16x8 kv = *(const bf16x8*)(rp + seg * 8 + j * 32);
    if (INIT) {
      sum += (float)kv[0] + (float)kv[1] + (float)kv[2] + (float)kv[3] +
             (float)kv[4] + (float)kv[5] + (float)kv[6] + (float)kv[7];
    } else {
      const float4* xp = (const float4*)&xs[seg * 8 + j * 32];
      float4 x0 = xp[0], x1 = xp[1];
      sum += (float)kv[0] * x0.x + (float)kv[1] * x0.y + (float)kv[2] * x0.z +
             (float)kv[3] * x0.w + (float)kv[4] * x1.x + (float)kv[5] * x1.y +
             (float)kv[6] * x1.z + (float)kv[7] * x1.w;
    }
  }
  if (INIT) sum *= (1.0f / 512.0f);
  sum += __shfl_xor(sum, 1);
  sum += __shfl_xor(sum, 2);
  if (seg == 0)
    y[b * 512 + row] = powf(w[b * 512 + row] / sum, 10.0f / 10.1f);
}

// ---------- Sinkhorn closed-form extrapolation to iteration 100 ----------
// args: (prev u, curr u, prev v, curr v); x_100 = x_M * exp(rho_M * G)
__global__ __launch_bounds__(512) void sink_final_kernel(
    const float* __restrict__ ua, const float* __restrict__ ub,
    const float* __restrict__ va, const float* __restrict__ vb,
    float* __restrict__ u_out, float* __restrict__ v_out, float Gf) {
  const int b = blockIdx.x, t = threadIdx.x, idx = b * 512 + t;
  const float ubv = ub[idx], vbv = vb[idx];
  float su = logf(ubv / ua[idx]);
  float sv = logf(vbv / va[idx]);
  #pragma unroll
  for (int ofs = 32; ofs > 0; ofs >>= 1) {
    su += __shfl_down(su, ofs);
    sv += __shfl_down(sv, ofs);
  }
  __shared__ float r0[8], r1[8];
  __shared__ float mu, mv;
  if ((t & 63) == 0) { r0[t >> 6] = su; r1[t >> 6] = sv; }
  __syncthreads();
  if (t == 0) {
    float a = 0.f, c = 0.f;
    #pragma unroll
    for (int i = 0; i < 8; i++) { a += r0[i]; c += r1[i]; }
    mu = a / 512.f; mv = c / 512.f;
  }
  __syncthreads();
  u_out[idx] = ubv * expf(Gf * mu);
  v_out[idx] = vbv * expf(Gf * mv);
}

extern "C" void kernel_launch(void* const* d_in, const int* in_sizes, int n_in,
                              void* d_out, int out_size, void* d_ws, size_t ws_size,
                              hipStream_t stream) {
  (void)in_sizes; (void)n_in; (void)out_size; (void)ws_size;
  const float* src = (const float*)d_in[0];   // [32,512,1024]
  const float* tgt = (const float*)d_in[1];   // [32,512,1024]
  const int* smask = (const int*)d_in[2];     // [32,512]
  const int* gmask = (const int*)d_in[3];     // [32,512]
  const float* W   = (const float*)d_in[4];   // [1024,1024]
  const float* bias = (const float*)d_in[5];  // [1024]
  float* out = (float*)d_out;                 // [32,512,1024]

  uint8_t* ws = (uint8_t*)d_ws;
  bf16_t* s_bf  = (bf16_t*)(ws + 0);          // 32 MB
  bf16_t* Kmat  = (bf16_t*)(ws + 0);          // reuse after gemm1: 16 MB
  bf16_t* KTmat = (bf16_t*)(ws + 16777216);   // 16 MB
  bf16_t* W_bf  = (bf16_t*)(ws + 33554432);   // 2 MB
  float* ua = (float*)(ws + 33554432);        // overwrite W_bf after gemm1
  float* ub = ua + 16384;
  float* va = ub + 16384;
  float* vb = va + 16384;
  bf16_t* g_bf  = (bf16_t*)(ws + 35651584);   // 32 MB
  bf16_t* t_bf  = (bf16_t*)(ws + 69206016);   // 32 MB
  bf16_t* gTv   = (bf16_t*)(ws + 69206016);   // reuse after gemm2
  float* s2  = (float*)(ws + 102760448);
  float* g2  = s2 + 16384;
  float* swv = g2 + 16384;
  float* gwv = swv + 16384;
  float* uv  = gwv + 16384;
  float* vv  = uv + 16384;

  // 1. conversions + g norms; zero s2 for fused-norm atomics
  cvt2_kernel<<<8704, 256, 0, stream>>>(src, s_bf, 2097152, W, W_bf);
  prep_g_kernel<<<16384, 128, 0, stream>>>(tgt, g_bf, g2);
  hipMemsetAsync(s2, 0, 16384 * sizeof(float), stream);

  // 2. t = s @ W^T + b  (M=16384,N=1024,K=1024) + fused row norms -> s2
  gemm_bt_kernel<0, 8, 128><<<1024, 256, 0, stream>>>(
      s_bf, W_bf, 1024, 0, 0, t_bf, 0, 1024, bias,
      nullptr, nullptr, nullptr, nullptr, nullptr, s2);

  // 3. weights (both sides, one dispatch)
  weights2_kernel<<<64, 512, 0, stream>>>(s2, smask, swv, g2, gmask, gwv);

  // 4. K = exp(-10*cost)  (per batch 512x512, K=1024)
  gemm_bt_kernel<1, 4, 4><<<512, 256, 0, stream>>>(
      t_bf, g_bf, 1024, (size_t)512 * 1024, (size_t)512 * 1024,
      Kmat, (size_t)512 * 512, 512, nullptr, s2, g2, swv, gwv, nullptr, nullptr);

  // 5. K^T (wide transpose)
  wide_transpose_kernel<0><<<dim3(8, 16, 32), 256, 0, stream>>>(
      Kmat, KTmat, nullptr, NS, NG);

  // 6. Sinkhorn: 3 real iterations (6 passes) + extrapolation.
  // u1->ua v1->va u2->ub v2->vb u3->ua v3->va; ratios (ub,ua),(vb,va).
  dim3 pg(NS / 64, NBATCH);
  sink_pass_kernel<1><<<pg, 256, 0, stream>>>(Kmat, nullptr, swv, ua);   // u1
  sink_pass_kernel<0><<<pg, 256, 0, stream>>>(KTmat, ua, gwv, va);       // v1
  sink_pass_kernel<0><<<pg, 256, 0, stream>>>(Kmat, va, swv, ub);        // u2
  sink_pass_kernel<0><<<pg, 256, 0, stream>>>(KTmat, ub, gwv, vb);       // v2
  sink_pass_kernel<0><<<pg, 256, 0, stream>>>(Kmat, vb, swv, ua);        // u3
  sink_pass_kernel<0><<<pg, 256, 0, stream>>>(KTmat, ua, gwv, va);       // v3

  // G = sum_{j=1}^{100-M_REAL} fi^(2j) in double
  double fi2 = (10.0 / 10.1) * (10.0 / 10.1);
  double Gd = 0.0, pd = 1.0;
  for (int j = 0; j < (N_TOT - M_REAL); j++) { pd *= fi2; Gd += pd; }
  sink_final_kernel<<<32, 512, 0, stream>>>(ub, ua, vb, va, uv, vv, (float)Gd);

  // 7. gTv[h][g] = v[g]*g[g][h] (wide transpose + scale)
  wide_transpose_kernel<1><<<dim3(16, 16, 32), 256, 0, stream>>>(
      g_bf, gTv, vv, NG, NH);

  // 8. aligned = u .* (K @ gTv)  (per batch 512x1024, K=512)
  gemm_bt_kernel<2, 8, 4><<<1024, 256, 0, stream>>>(
      Kmat, gTv, 512, (size_t)512 * 512, (size_t)1024 * 512,
      out, (size_t)512 * 1024, 1024, nullptr, nullptr, nullptr, nullptr, nullptr, uv, nullptr);
}